// Round 9
// baseline (177.372 us; speedup 1.0000x reference)
//
#include <hip/hip_runtime.h>

// Fused double-softmax attention, fp32 in/out, f16 MFMA for QK^T and PV.
// B=4 H=8 S=1024 D=64. Outputs: context [B,H,S,D] then attn [B,H,S,S].
// R9: maskless Phase A (mask folded into Phase B as coalesced int4 +
// denominator correction), unroll-2 chunk loops, reg-held outA write.
typedef _Float16 f16;
typedef _Float16 f16x8 __attribute__((ext_vector_type(8)));
typedef _Float16 f16x4 __attribute__((ext_vector_type(4)));
typedef float f32x4 __attribute__((ext_vector_type(4)));

constexpr int B_ = 4, H_ = 8, S_ = 1024, D_ = 64;
constexpr int BQ = 16;        // q rows per block
constexpr int NT = 512;       // 8 waves
constexpr int KC = 128;       // k per chunk (one 16-col tile per wave)
constexpr int QH_LD = 72;     // Qh row stride in f16
constexpr int SC_LD = 1032;   // sch row stride in f16

__device__ __forceinline__ float wred(float v) {
#pragma unroll
  for (int off = 32; off > 0; off >>= 1) v += __shfl_xor(v, off);
  return v;
}

__global__ __launch_bounds__(NT)
void fused_attn(const float* __restrict__ Q, const float* __restrict__ K,
                const float* __restrict__ V, const int* __restrict__ mask,
                const float* __restrict__ adj, const float* __restrict__ dist,
                const float* __restrict__ cw, const float* __restrict__ cb,
                float* __restrict__ outC, float* __restrict__ outA)
{
  __shared__ __align__(16) f16 Qh[BQ * QH_LD];     // 2.3 KB
  __shared__ __align__(16) f16 sch[BQ * SC_LD];    // 33.0 KB
  __shared__ __align__(16) float fscr[NT * 4];     // 8 KB
  __shared__ float rs1w[8][16];
  __shared__ float sall[BQ];
  __shared__ float rinv2[BQ];

  const int tid = threadIdx.x;
  // bijective XCD swizzle: 2048 blocks = 8 XCDs x 256 (4 heads per XCD)
  const int sw = (blockIdx.x & 7) * 256 + (blockIdx.x >> 3);
  const int qt = sw & 63;
  const int bh = sw >> 6;
  const int q0 = qt * BQ;
  const int wv = tid >> 6;    // wave 0..7
  const int ln = tid & 63;
  const int lg = ln >> 4;     // lane group 0..3
  const int li = ln & 15;

  const float* Qp = Q + ((size_t)bh * S_ + q0) * D_;
  const float* Kp = K + (size_t)bh * S_ * D_;
  const float* Vp = V + (size_t)bh * S_ * D_;
  const size_t rb = ((size_t)bh * S_ + q0) * S_;

  // stage Q tile -> f16
  if (tid < 256) {
    const int q = tid >> 4, c4 = (tid & 15) << 2;
    float4 v = *(const float4*)(Qp + q * D_ + c4);
    f16* d = &Qh[q * QH_LD + c4];
    d[0] = (f16)v.x; d[1] = (f16)v.y; d[2] = (f16)v.z; d[3] = (f16)v.w;
  }
  const float w0 = cw[0], w1 = cw[1], w2 = cw[2], bb = cb[0];
  __syncthreads();                                  // (1)

  // hoist Q fragments (A operand; lane li = q-row li, k = s*32 + lg*8)
  f16x8 aq0 = *(const f16x8*)&Qh[li * QH_LD + 0 * 32 + lg * 8];
  f16x8 aq1 = *(const f16x8*)&Qh[li * QH_LD + 1 * 32 + lg * 8];

  // ===== Phase A: UNMASKED e = exp(QK^T/8) via MFMA; K straight from global ==
  // wave wv owns k-cols n0 + c*KC; rs accumulates f16-rounded full-row sums.
  const int n0 = wv * 16;
  float rs[4] = {0.f, 0.f, 0.f, 0.f};
#pragma unroll 2
  for (int c = 0; c < 8; ++c) {
    const int kg = c * KC + n0 + li;
    const float* Kr = Kp + (size_t)kg * D_ + lg * 8;
    const float4 ka = *(const float4*)(Kr + 0);
    const float4 kb = *(const float4*)(Kr + 4);
    const float4 kc2 = *(const float4*)(Kr + 32);
    const float4 kd = *(const float4*)(Kr + 36);
    f16x8 b0, b1;
    b0[0] = (f16)ka.x; b0[1] = (f16)ka.y; b0[2] = (f16)ka.z; b0[3] = (f16)ka.w;
    b0[4] = (f16)kb.x; b0[5] = (f16)kb.y; b0[6] = (f16)kb.z; b0[7] = (f16)kb.w;
    b1[0] = (f16)kc2.x; b1[1] = (f16)kc2.y; b1[2] = (f16)kc2.z; b1[3] = (f16)kc2.w;
    b1[4] = (f16)kd.x; b1[5] = (f16)kd.y; b1[6] = (f16)kd.z; b1[7] = (f16)kd.w;
    f32x4 acc = {0.f, 0.f, 0.f, 0.f};
    acc = __builtin_amdgcn_mfma_f32_16x16x32_f16(aq0, b0, acc, 0, 0, 0);
    acc = __builtin_amdgcn_mfma_f32_16x16x32_f16(aq1, b1, acc, 0, 0, 0);
#pragma unroll
    for (int r = 0; r < 4; ++r) {            // D[m][n]: m=lg*4+r, n=li
      const int m = lg * 4 + r;
      const f16 ef = (f16)__expf(acc[r] * 0.125f);
      sch[m * SC_LD + kg] = ef;
      rs[r] += (float)ef;                    // rounded sum (consistent with B)
    }
  }
#pragma unroll
  for (int r = 0; r < 4; ++r) {              // reduce over 16 lanes per group
    rs[r] += __shfl_xor(rs[r], 1); rs[r] += __shfl_xor(rs[r], 2);
    rs[r] += __shfl_xor(rs[r], 4); rs[r] += __shfl_xor(rs[r], 8);
  }
  if (li == 0) {
#pragma unroll
    for (int r = 0; r < 4; ++r) rs1w[wv][lg * 4 + r] = rs[r];
  }
  __syncthreads();                                  // (2) sch + rs1w visible
  if (tid < BQ) {
    float t = 0.f;
#pragma unroll
    for (int w = 0; w < 8; ++w) t += rs1w[w][tid];
    sall[tid] = t;                           // full-row sum (incl. masked)
  }
  __syncthreads();                                  // (3)

  // ===== Phase B: mask fold + conv-softmax; wave -> rows 2wv, 2wv+1 ==========
#pragma unroll
  for (int rr = 0; rr < 2; ++rr) {
    const int q = 2 * wv + rr;
    const size_t base = rb + (size_t)q * S_;
    // pass 1: coalesced mask, denominator correction, plant -1 sentinels
    float corr = 0.f;
#pragma unroll
    for (int swp = 0; swp < 4; ++swp) {
      const int k4 = swp * 256 + ln * 4;
      const int4 mv = *(const int4*)(mask + base + k4);
      f16x4 ef = *(const f16x4*)&sch[q * SC_LD + k4];
      corr += (mv.x ? (float)ef[0] : 0.f) + (mv.y ? (float)ef[1] : 0.f)
            + (mv.z ? (float)ef[2] : 0.f) + (mv.w ? (float)ef[3] : 0.f);
      f16x4 sf;
      sf[0] = mv.x ? (f16)(-1.f) : ef[0];
      sf[1] = mv.y ? (f16)(-1.f) : ef[1];
      sf[2] = mv.z ? (f16)(-1.f) : ef[2];
      sf[3] = mv.w ? (f16)(-1.f) : ef[3];
      *(f16x4*)&sch[q * SC_LD + k4] = sf;
    }
    corr = wred(corr);
    const float i1 = 1.f / (sall[q] - corr);
    // pass 2: aw = exp(w0*p + w1*dist + w2*adj + b); keep aw in registers
    f16x4 afr[4];
    float s2 = 0.f;
#pragma unroll
    for (int swp = 0; swp < 4; ++swp) {
      const int k4 = swp * 256 + ln * 4;
      f16x4 ef = *(const f16x4*)&sch[q * SC_LD + k4];
      float4 dv = *(const float4*)(dist + base + k4);
      float4 av = *(const float4*)(adj + base + k4);
      const float e0 = (float)ef[0], e1 = (float)ef[1];
      const float e2 = (float)ef[2], e3 = (float)ef[3];
      const float a0 = (e0 < 0.f) ? 0.f : __expf(w0 * (e0 * i1) + w1 * dv.x + w2 * av.x + bb);
      const float a1 = (e1 < 0.f) ? 0.f : __expf(w0 * (e1 * i1) + w1 * dv.y + w2 * av.y + bb);
      const float a2 = (e2 < 0.f) ? 0.f : __expf(w0 * (e2 * i1) + w1 * dv.z + w2 * av.z + bb);
      const float a3 = (e3 < 0.f) ? 0.f : __expf(w0 * (e3 * i1) + w1 * dv.w + w2 * av.w + bb);
      f16x4 af; af[0] = (f16)a0; af[1] = (f16)a1; af[2] = (f16)a2; af[3] = (f16)a3;
      *(f16x4*)&sch[q * SC_LD + k4] = af;
      afr[swp] = af;
      s2 += a0 + a1 + a2 + a3;
    }
    s2 = wred(s2);
    const float i2 = 1.f / s2;
    if (ln == 0) rinv2[q] = i2;
    // pass 3: normalized attn straight from registers
#pragma unroll
    for (int swp = 0; swp < 4; ++swp) {
      const int k4 = swp * 256 + ln * 4;
      float4 o = make_float4((float)afr[swp][0] * i2, (float)afr[swp][1] * i2,
                             (float)afr[swp][2] * i2, (float)afr[swp][3] * i2);
      *(float4*)(outA + base + k4) = o;
    }
  }
  __syncthreads();                                  // (4) sch aw-values visible

  // ===== Phase C: ctx = P(f16) x V(f16); V^T fragments straight from global ==
  const int ntile = wv >> 1;
  const int spair = (wv & 1) * 2;
  const int d0 = ntile * 16 + li;
  f32x4 cacc = {0.f, 0.f, 0.f, 0.f};
#pragma unroll 2
  for (int c = 0; c < 8; ++c) {
#pragma unroll
    for (int u = 0; u < 2; ++u) {
      const int s = spair + u;
      const float* Vc = Vp + (size_t)(c * KC + s * 32 + lg * 8) * D_ + d0;
      f16x8 bfr;
#pragma unroll
      for (int j = 0; j < 8; ++j) bfr[j] = (f16)Vc[(size_t)j * D_];
      f16x8 a = *(const f16x8*)&sch[li * SC_LD + c * KC + s * 32 + lg * 8];
      cacc = __builtin_amdgcn_mfma_f32_16x16x32_f16(a, bfr, cacc, 0, 0, 0);
    }
  }
  *(f32x4*)&fscr[tid * 4] = cacc;
  __syncthreads();                                  // (5)
  if (tid < 256) {                    // combine wave pairs, scale, write ctx
    const int t = tid >> 6, l2 = tid & 63;
    const int g2 = l2 >> 4, n = l2 & 15;
    f32x4 p  = *(const f32x4*)&fscr[((2 * t) * 64 + l2) * 4];
    f32x4 p2 = *(const f32x4*)&fscr[((2 * t + 1) * 64 + l2) * 4];
#pragma unroll
    for (int r = 0; r < 4; ++r) {
      const int m = g2 * 4 + r;
      outC[((size_t)bh * S_ + q0 + m) * D_ + t * 16 + n] = (p[r] + p2[r]) * rinv2[m];
    }
  }
}

extern "C" void kernel_launch(void* const* d_in, const int* in_sizes, int n_in,
                              void* d_out, int out_size, void* d_ws, size_t ws_size,
                              hipStream_t stream) {
  const float* Q    = (const float*)d_in[0];
  const float* K    = (const float*)d_in[1];
  const float* V    = (const float*)d_in[2];
  const int*   mask = (const int*)  d_in[3];
  const float* adj  = (const float*)d_in[4];
  const float* dist = (const float*)d_in[5];
  const float* cw   = (const float*)d_in[6];
  const float* cb   = (const float*)d_in[7];

  float* outC = (float*)d_out;                                   // [B,H,S,D]
  float* outA = outC + (size_t)B_ * H_ * S_ * D_;                // [B,H,S,S]

  fused_attn<<<dim3(B_ * H_ * (S_ / BQ)), NT, 0, stream>>>(
      Q, K, V, mask, adj, dist, cw, cb, outC, outA);
}